// Round 2
// baseline (796.916 us; speedup 1.0000x reference)
//
#include <hip/hip_runtime.h>

typedef __bf16 bf16;
typedef __bf16 bf16x4 __attribute__((ext_vector_type(4)));
typedef __bf16 bf16x8 __attribute__((ext_vector_type(8)));
typedef float  f32x4  __attribute__((ext_vector_type(4)));

#define MFMA16(a, b, c) __builtin_amdgcn_mfma_f32_16x16x32_bf16((a), (b), (c), 0, 0, 0)

constexpr int N_NODES = 50000;
constexpr int N_EDGES = 800000;
constexpr int D = 64;

// ---------------- fast-path workspace layout (~112.7 MB) ----------------
constexpr size_t OFF_FBUF   = 0;                       // bf16[N_NODES*D]   6.4e6 B
constexpr size_t OFF_H2     = 6400000;                 // bf16[N_EDGES*D] 102.4e6 B
constexpr size_t OFF_EPERM  = 108800000;               // int[N_EDGES]      3.2e6 B (CSR slot -> edge id)
constexpr size_t OFF_ROWPTR = 112000000;               // int[N_NODES+1]
constexpr size_t OFF_CURSOR = 112200064;               // int[N_NODES]
constexpr size_t OFF_COUNTS = 112400064;               // int[N_NODES]
constexpr size_t OFF_WBF    = 112600064;               // bf16[28672]
constexpr size_t OFF_FLAGS  = 112657408;               // int[2]
constexpr size_t WS_FAST_NEED = 112700000;

// ---------------- slow-path (R2 fallback) layout (~12.9 MB) --------------
constexpr size_t S_SBUF  = 0;                          // f32[N_NODES*D] 12.8e6 B
constexpr size_t S_FLAGS = 12800000;

// legacy strides for fallback kernels
constexpr int XS_STRIDE = 200;
constexpr int HS_STRIDE = 72;
constexpr int X2_STRIDE = 136;

// ---------------------------------------------------------------------------
// Dtype detection (proven): flags[0]=1 -> f32 arrays; flags[1]=1 -> i64 idx.
// ---------------------------------------------------------------------------
__global__ void detect_kernel(const void* __restrict__ feat,
                              const void* __restrict__ eidx,
                              int* __restrict__ flags)
{
    __shared__ int c_bf[64], c_nz[64];
    const int t = threadIdx.x;
    const unsigned short* h = (const unsigned short*)feat;
    int c = 0;
    #pragma unroll
    for (int j = 0; j < 8; ++j) {
        const unsigned short v = h[(t * 8 + j) * 2];
        const int e8 = (v >> 7) & 0xFF;
        c += (e8 >= 97 && e8 <= 157) ? 1 : 0;
    }
    c_bf[t] = c;
    const int* ei = (const int*)eidx;
    int nz = 0;
    #pragma unroll
    for (int j = 0; j < 2; ++j)
        nz += (ei[(t * 2 + j) * 2 + 1] != 0) ? 1 : 0;
    c_nz[t] = nz;
    __syncthreads();
    if (t == 0) {
        int s = 0, s2 = 0;
        for (int i = 0; i < 64; ++i) { s += c_bf[i]; s2 += c_nz[i]; }
        flags[0] = (s < 384) ? 1 : 0;
        flags[1] = (s2 < 4) ? 1 : 0;
    }
}

__device__ inline bf16x8 ld8(const void* base, size_t off, int f32f) {
    if (f32f) {
        const float* p = (const float*)base + off;
        const float4 a = *(const float4*)p;
        const float4 b = *(const float4*)(p + 4);
        bf16x8 r;
        r[0] = (bf16)a.x; r[1] = (bf16)a.y; r[2] = (bf16)a.z; r[3] = (bf16)a.w;
        r[4] = (bf16)b.x; r[5] = (bf16)b.y; r[6] = (bf16)b.z; r[7] = (bf16)b.w;
        return r;
    }
    return *(const bf16x8*)((const bf16*)base + off);
}

__device__ inline float ldf(const void* base, int i, int f32f) {
    return f32f ? ((const float*)base)[i] : (float)((const bf16*)base)[i];
}

__device__ inline int gidx(const void* e, size_t i, int i64f) {
    return i64f ? (int)((const long long*)e)[i] : ((const int*)e)[i];
}

// ---------------------------------------------------------------------------
// Weight pre-conversion: wbf = bf16[ W1(12288) | W2(4096) | W3(8192) | W4(4096) ]
// ---------------------------------------------------------------------------
__global__ void prep_kernel(const void* __restrict__ W1, const void* __restrict__ W2,
                            const void* __restrict__ W3, const void* __restrict__ W4,
                            bf16* __restrict__ wbf, const int* __restrict__ flags)
{
    const int F32 = flags[0];
    for (int i = threadIdx.x; i < 28672; i += 256) {
        const void* src; int off;
        if (i < 12288)      { src = W1; off = i; }
        else if (i < 16384) { src = W2; off = i - 12288; }
        else if (i < 24576) { src = W3; off = i - 16384; }
        else                { src = W4; off = i - 24576; }
        wbf[i] = F32 ? (bf16)((const float*)src)[off] : ((const bf16*)src)[off];
    }
}

// feat -> bf16 table (4 elems/thread; grid 3125*256 = 800000 exact)
__global__ void conv_feat_kernel(const void* __restrict__ feat, bf16* __restrict__ fbuf,
                                 const int* __restrict__ flags)
{
    const int F32 = flags[0];
    const int i = blockIdx.x * 256 + threadIdx.x;     // 0..799999 (x4 elems)
    if (F32) {
        const float4 v = ((const float4*)feat)[i];
        bf16x4 r; r[0] = (bf16)v.x; r[1] = (bf16)v.y; r[2] = (bf16)v.z; r[3] = (bf16)v.w;
        ((bf16x4*)fbuf)[i] = r;
    } else {
        ((bf16x4*)fbuf)[i] = ((const bf16x4*)feat)[i];
    }
}

// ---------------------------------------------------------------------------
// CSR build: histogram -> scan -> eperm (CSR slot -> edge id).
// NOTE (R1): inverted vs previous version. Edge kernel now writes h2 rows
// SEQUENTIALLY at h2ws[e]; the node kernel follows eperm on its READ side.
// Scattered 128B HBM writes were the edge kernel's bottleneck (1.14 TB/s,
// all pipes idle); scattered reads have MLP + L3 absorption on their side.
// ---------------------------------------------------------------------------
__global__ void hist_kernel(const void* __restrict__ eidx, int* __restrict__ counts,
                            const int* __restrict__ flags)
{
    const int I64 = flags[1];
    const int e = blockIdx.x * 256 + threadIdx.x;
    atomicAdd(&counts[gidx(eidx, e, I64)], 1);
}

__global__ void scan_kernel(const int* __restrict__ counts, int* __restrict__ rowptr,
                            int* __restrict__ cursor)
{
    __shared__ int part[256];
    const int t = threadIdx.x;
    const int base = t * 196;
    int s = 0;
    for (int i = 0; i < 196; ++i) {
        const int idx = base + i;
        if (idx < N_NODES) s += counts[idx];
    }
    part[t] = s;
    __syncthreads();
    if (t == 0) {
        int acc = 0;
        for (int i = 0; i < 256; ++i) { const int v = part[i]; part[i] = acc; acc += v; }
        rowptr[N_NODES] = acc;
    }
    __syncthreads();
    int acc = part[t];
    for (int i = 0; i < 196; ++i) {
        const int idx = base + i;
        if (idx < N_NODES) {
            rowptr[idx] = acc;
            cursor[idx] = acc;
            acc += counts[idx];
        }
    }
}

__global__ void fill_kernel(const void* __restrict__ eidx, int* __restrict__ cursor,
                            int* __restrict__ eperm, const int* __restrict__ flags)
{
    const int I64 = flags[1];
    const int e = blockIdx.x * 256 + threadIdx.x;
    const int src = gidx(eidx, e, I64);
    const int p = atomicAdd(&cursor[src], 1);
    eperm[p] = e;                      // inverse mapping: CSR slot -> edge id
}

// ---------------------------------------------------------------------------
// FAST edge kernel: one wave = 16 edges, barrier-free, A-frags direct from
// global, h2 rows -> h2ws[e] (bf16, SEQUENTIAL coalesced 32B/lane stores).
// ---------------------------------------------------------------------------
__global__ __launch_bounds__(256) void edge_fast(
    const bf16* __restrict__ fbuf, const void* __restrict__ eidx,
    const void* __restrict__ efeat,
    const bf16* __restrict__ wbf, const void* __restrict__ b1, const void* __restrict__ b2,
    bf16* __restrict__ h2ws, const int* __restrict__ flags)
{
    __shared__ bf16 hs[4][16 * 72];   // h1 C->A roundtrip, wave-private
    __shared__ bf16 os[4][16 * 72];   // h2 store staging, wave-private

    const int t    = threadIdx.x;
    const int wave = t >> 6;
    const int lane = t & 63;
    const int lrow = lane & 15;
    const int quad = lane >> 4;
    const int e0   = blockIdx.x * 64 + wave * 16;   // this wave's 16 edges
    const int F32  = flags[0], I64 = flags[1];

    const int e   = e0 + lrow;
    const int src = gidx(eidx, (size_t)e, I64);
    const int dst = gidx(eidx, (size_t)N_EDGES + e, I64);

    const bf16* W1b = wbf;            // [64][192]
    const bf16* W2b = wbf + 12288;    // [64][64]

    // GEMM1: K=192. A row = [fbuf[src] | efeat[e] | fbuf[dst]]; part = k>>1.
    f32x4 acc[4] = {{0,0,0,0},{0,0,0,0},{0,0,0,0},{0,0,0,0}};
    #pragma unroll
    for (int k = 0; k < 6; ++k) {
        const int po = (k & 1) * 32 + quad * 8;     // offset within the 64-elem part
        bf16x8 a;
        if (k < 2)      a = *(const bf16x8*)&fbuf[(size_t)src * D + po];
        else if (k < 4) a = ld8(efeat, (size_t)e * D + po, F32);
        else            a = *(const bf16x8*)&fbuf[(size_t)dst * D + po];
        #pragma unroll
        for (int n = 0; n < 4; ++n) {
            const bf16x8 b = *(const bf16x8*)&W1b[(n * 16 + lrow) * 192 + k * 32 + quad * 8];
            acc[n] = MFMA16(a, b, acc[n]);
        }
    }

    // ReLU + b1; C-layout -> wave-private LDS (A-layout for GEMM2). No barrier.
    #pragma unroll
    for (int n = 0; n < 4; ++n) {
        const int col  = n * 16 + lrow;
        const float bb = ldf(b1, col, F32);
        #pragma unroll
        for (int r = 0; r < 4; ++r) {
            float v = acc[n][r] + bb;
            v = v > 0.f ? v : 0.f;
            hs[wave][(quad * 4 + r) * 72 + col] = (bf16)v;
        }
    }

    // GEMM2: K=64.
    f32x4 acc2[4] = {{0,0,0,0},{0,0,0,0},{0,0,0,0},{0,0,0,0}};
    #pragma unroll
    for (int k = 0; k < 2; ++k) {
        const bf16x8 a = *(const bf16x8*)&hs[wave][lrow * 72 + k * 32 + quad * 8];
        #pragma unroll
        for (int n = 0; n < 4; ++n) {
            const bf16x8 b = *(const bf16x8*)&W2b[(n * 16 + lrow) * D + k * 32 + quad * 8];
            acc2[n] = MFMA16(a, b, acc2[n]);
        }
    }

    // h2 + b2 -> os (wave-private), then coalesced SEQUENTIAL 32B/lane store.
    #pragma unroll
    for (int n = 0; n < 4; ++n) {
        const int col  = n * 16 + lrow;
        const float bb = ldf(b2, col, F32);
        #pragma unroll
        for (int r = 0; r < 4; ++r)
            os[wave][(quad * 4 + r) * 72 + col] = (bf16)(acc2[n][r] + bb);
    }

    const int row = lane >> 2;          // 0..15 (edge row within wave)
    const int seg = lane & 3;           // 16-col segment
    const bf16x8 v0 = *(const bf16x8*)&os[wave][row * 72 + seg * 16];
    const bf16x8 v1 = *(const bf16x8*)&os[wave][row * 72 + seg * 16 + 8];
    *(bf16x8*)&h2ws[(size_t)(e0 + row) * D + seg * 16]     = v0;
    *(bf16x8*)&h2ws[(size_t)(e0 + row) * D + seg * 16 + 8] = v1;
}

// ---------------------------------------------------------------------------
// FAST node kernel: CSR segment-sum gathering h2ws[eperm[j]] (scattered reads,
// 4-deep unroll for MLP; h2 is largely L3-resident right after edge_fast),
// then MLP. 64 nodes/block; gather phase: 4 lanes per node, 16 cols each.
// ---------------------------------------------------------------------------
__global__ __launch_bounds__(256) void node_fast(
    const bf16* __restrict__ fbuf, const bf16* __restrict__ h2ws,
    const int* __restrict__ rowptr, const int* __restrict__ eperm,
    const bf16* __restrict__ wbf, const void* __restrict__ b3, const void* __restrict__ b4,
    void* __restrict__ out, const int* __restrict__ flags)
{
    __shared__ bf16 xs[64 * X2_STRIDE];
    __shared__ bf16 h3s[64 * HS_STRIDE];

    const int t  = threadIdx.x;
    const int r0 = blockIdx.x * 64;
    const int F32 = flags[0];

    // segment sum: thread t -> node r0 + (t>>2), col segment (t&3)*16
    {
        const int nloc = t >> 2;
        const int node = r0 + nloc;
        const int seg  = t & 3;
        float accv[16];
        #pragma unroll
        for (int i = 0; i < 16; ++i) accv[i] = 0.f;
        bf16x8 f0 = {0,0,0,0,0,0,0,0}, f1 = {0,0,0,0,0,0,0,0};
        if (node < N_NODES) {
            f0 = *(const bf16x8*)&fbuf[(size_t)node * D + seg * 16];
            f1 = *(const bf16x8*)&fbuf[(size_t)node * D + seg * 16 + 8];
            const int jb = rowptr[node], je = rowptr[node + 1];
            int j = jb;
            for (; j + 4 <= je; j += 4) {
                const int ea = eperm[j],     eb = eperm[j + 1];
                const int ec = eperm[j + 2], ed = eperm[j + 3];
                const bf16x8 a0 = *(const bf16x8*)&h2ws[(size_t)ea * D + seg * 16];
                const bf16x8 a1 = *(const bf16x8*)&h2ws[(size_t)ea * D + seg * 16 + 8];
                const bf16x8 b0 = *(const bf16x8*)&h2ws[(size_t)eb * D + seg * 16];
                const bf16x8 b1v = *(const bf16x8*)&h2ws[(size_t)eb * D + seg * 16 + 8];
                const bf16x8 c0 = *(const bf16x8*)&h2ws[(size_t)ec * D + seg * 16];
                const bf16x8 c1 = *(const bf16x8*)&h2ws[(size_t)ec * D + seg * 16 + 8];
                const bf16x8 d0 = *(const bf16x8*)&h2ws[(size_t)ed * D + seg * 16];
                const bf16x8 d1 = *(const bf16x8*)&h2ws[(size_t)ed * D + seg * 16 + 8];
                #pragma unroll
                for (int i = 0; i < 8; ++i) {
                    accv[i]     += ((float)a0[i] + (float)b0[i]) + ((float)c0[i] + (float)d0[i]);
                    accv[i + 8] += ((float)a1[i] + (float)b1v[i]) + ((float)c1[i] + (float)d1[i]);
                }
            }
            for (; j < je; ++j) {
                const int ea = eperm[j];
                const bf16x8 a0 = *(const bf16x8*)&h2ws[(size_t)ea * D + seg * 16];
                const bf16x8 a1 = *(const bf16x8*)&h2ws[(size_t)ea * D + seg * 16 + 8];
                #pragma unroll
                for (int i = 0; i < 8; ++i) {
                    accv[i]     += (float)a0[i];
                    accv[i + 8] += (float)a1[i];
                }
            }
        }
        bf16x8 s0, s1;
        #pragma unroll
        for (int i = 0; i < 8; ++i) {
            s0[i] = (bf16)((float)f0[i] + accv[i]);
            s1[i] = (bf16)((float)f1[i] + accv[i + 8]);
        }
        *(bf16x8*)&xs[nloc * X2_STRIDE + seg * 16]          = f0;
        *(bf16x8*)&xs[nloc * X2_STRIDE + seg * 16 + 8]      = f1;
        *(bf16x8*)&xs[nloc * X2_STRIDE + 64 + seg * 16]     = s0;
        *(bf16x8*)&xs[nloc * X2_STRIDE + 64 + seg * 16 + 8] = s1;
    }
    __syncthreads();

    const int wave = t >> 6;
    const int lane = t & 63;
    const int m0   = wave * 16;
    const int lrow = lane & 15;
    const int quad = lane >> 4;
    const bf16* W3b = wbf + 16384;   // [64][128]
    const bf16* W4b = wbf + 24576;   // [64][64]

    // GEMM3: K=128
    f32x4 acc[4] = {{0,0,0,0},{0,0,0,0},{0,0,0,0},{0,0,0,0}};
    #pragma unroll
    for (int k = 0; k < 4; ++k) {
        const bf16x8 a = *(const bf16x8*)&xs[(m0 + lrow) * X2_STRIDE + k * 32 + quad * 8];
        #pragma unroll
        for (int n = 0; n < 4; ++n) {
            const bf16x8 b = *(const bf16x8*)&W3b[(n * 16 + lrow) * 128 + k * 32 + quad * 8];
            acc[n] = MFMA16(a, b, acc[n]);
        }
    }

    #pragma unroll
    for (int n = 0; n < 4; ++n) {
        const int col  = n * 16 + lrow;
        const float bb = ldf(b3, col, F32);
        #pragma unroll
        for (int r = 0; r < 4; ++r) {
            float v = acc[n][r] + bb;
            v = v > 0.f ? v : 0.f;
            h3s[(m0 + quad * 4 + r) * HS_STRIDE + col] = (bf16)v;
        }
    }

    // GEMM4: K=64 (h3s rows are wave-private; no barrier needed)
    f32x4 acc2[4] = {{0,0,0,0},{0,0,0,0},{0,0,0,0},{0,0,0,0}};
    #pragma unroll
    for (int k = 0; k < 2; ++k) {
        const bf16x8 a = *(const bf16x8*)&h3s[(m0 + lrow) * HS_STRIDE + k * 32 + quad * 8];
        #pragma unroll
        for (int n = 0; n < 4; ++n) {
            const bf16x8 b = *(const bf16x8*)&W4b[(n * 16 + lrow) * D + k * 32 + quad * 8];
            acc2[n] = MFMA16(a, b, acc2[n]);
        }
    }

    #pragma unroll
    for (int n = 0; n < 4; ++n) {
        const int col  = n * 16 + lrow;
        const float bb = ldf(b4, col, F32);
        #pragma unroll
        for (int r = 0; r < 4; ++r) {
            const int node = r0 + m0 + quad * 4 + r;
            if (node < N_NODES) {
                const float v = acc2[n][r] + bb;
                if (F32) ((float*)out)[(size_t)node * D + col] = v;
                else     ((bf16*)out)[(size_t)node * D + col] = (bf16)v;
            }
        }
    }
}

// ---------------------------------------------------------------------------
// SLOW fallback = proven R2 kernels (global f32 atomic scatter), used only
// if ws_size is too small for the fast path.
// ---------------------------------------------------------------------------
__global__ __launch_bounds__(256) void edge_slow(
    const void* __restrict__ feat, const void* __restrict__ eidx,
    const void* __restrict__ efeat,
    const void* __restrict__ W1, const void* __restrict__ b1,
    const void* __restrict__ W2, const void* __restrict__ b2,
    float* __restrict__ sbuf, const int* __restrict__ flags)
{
    __shared__ bf16 xs[64 * XS_STRIDE];
    __shared__ bf16 h1s[64 * HS_STRIDE];
    __shared__ int  srcs[64];
    __shared__ int  fl[2];

    const int t  = threadIdx.x;
    const int e0 = blockIdx.x * 64;

    if (t < 2) fl[t] = flags[t];
    __syncthreads();
    const int F32 = fl[0], I64 = fl[1];

    if (t < 64) srcs[t] = gidx(eidx, e0 + t, I64);

    for (int i = t; i < 64 * 24; i += 256) {
        const int e    = i / 24;
        const int c    = i - e * 24;
        const int part = c >> 3;
        const int cc   = c & 7;
        size_t off;
        const void* base;
        if (part == 0)      { base = feat;  off = (size_t)gidx(eidx, e0 + e, I64) * D + cc * 8; }
        else if (part == 1) { base = efeat; off = (size_t)(e0 + e) * D + cc * 8; }
        else                { base = feat;  off = (size_t)gidx(eidx, (size_t)N_EDGES + e0 + e, I64) * D + cc * 8; }
        *(bf16x8*)&xs[e * XS_STRIDE + part * 64 + cc * 8] = ld8(base, off, F32);
    }
    __syncthreads();

    const int wave = t >> 6;
    const int lane = t & 63;
    const int m0   = wave * 16;
    const int lrow = lane & 15;
    const int quad = lane >> 4;

    f32x4 acc[4] = {{0,0,0,0},{0,0,0,0},{0,0,0,0},{0,0,0,0}};
    #pragma unroll
    for (int k = 0; k < 6; ++k) {
        const bf16x8 a = *(const bf16x8*)&xs[(m0 + lrow) * XS_STRIDE + k * 32 + quad * 8];
        #pragma unroll
        for (int n = 0; n < 4; ++n) {
            const bf16x8 b = ld8(W1, (size_t)(n * 16 + lrow) * 192 + k * 32 + quad * 8, F32);
            acc[n] = MFMA16(a, b, acc[n]);
        }
    }

    #pragma unroll
    for (int n = 0; n < 4; ++n) {
        const int col  = n * 16 + lrow;
        const float bb = ldf(b1, col, F32);
        #pragma unroll
        for (int r = 0; r < 4; ++r) {
            float v = acc[n][r] + bb;
            v = v > 0.f ? v : 0.f;
            h1s[(m0 + quad * 4 + r) * HS_STRIDE + col] = (bf16)v;
        }
    }
    __syncthreads();

    f32x4 acc2[4] = {{0,0,0,0},{0,0,0,0},{0,0,0,0},{0,0,0,0}};
    #pragma unroll
    for (int k = 0; k < 2; ++k) {
        const bf16x8 a = *(const bf16x8*)&h1s[(m0 + lrow) * HS_STRIDE + k * 32 + quad * 8];
        #pragma unroll
        for (int n = 0; n < 4; ++n) {
            const bf16x8 b = ld8(W2, (size_t)(n * 16 + lrow) * D + k * 32 + quad * 8, F32);
            acc2[n] = MFMA16(a, b, acc2[n]);
        }
    }

    #pragma unroll
    for (int n = 0; n < 4; ++n) {
        const int col  = n * 16 + lrow;
        const float bb = ldf(b2, col, F32);
        #pragma unroll
        for (int r = 0; r < 4; ++r) {
            const int e = m0 + quad * 4 + r;
            atomicAdd(&sbuf[(size_t)srcs[e] * D + col], acc2[n][r] + bb);
        }
    }
}

__global__ __launch_bounds__(256) void node_slow(
    const void* __restrict__ feat, const float* __restrict__ sbuf,
    const void* __restrict__ W3, const void* __restrict__ b3,
    const void* __restrict__ W4, const void* __restrict__ b4,
    void* __restrict__ out, const int* __restrict__ flags)
{
    __shared__ bf16 xs[64 * X2_STRIDE];
    __shared__ bf16 h3s[64 * HS_STRIDE];
    __shared__ int fl[1];

    const int t  = threadIdx.x;
    const int r0 = blockIdx.x * 64;

    if (t == 0) fl[0] = flags[0];
    __syncthreads();
    const int F32 = fl[0];

    for (int i = t; i < 64 * 8; i += 256) {
        const int r    = i >> 3;
        const int c    = i & 7;
        const int node = r0 + r;
        bf16x8 fv = {0,0,0,0,0,0,0,0};
        bf16x8 sv = {0,0,0,0,0,0,0,0};
        if (node < N_NODES) {
            fv = ld8(feat, (size_t)node * D + c * 8, F32);
            const float4 sa = *(const float4*)&sbuf[(size_t)node * D + c * 8];
            const float4 sb = *(const float4*)&sbuf[(size_t)node * D + c * 8 + 4];
            sv[0] = (bf16)((float)fv[0] + sa.x);
            sv[1] = (bf16)((float)fv[1] + sa.y);
            sv[2] = (bf16)((float)fv[2] + sa.z);
            sv[3] = (bf16)((float)fv[3] + sa.w);
            sv[4] = (bf16)((float)fv[4] + sb.x);
            sv[5] = (bf16)((float)fv[5] + sb.y);
            sv[6] = (bf16)((float)fv[6] + sb.z);
            sv[7] = (bf16)((float)fv[7] + sb.w);
        }
        *(bf16x8*)&xs[r * X2_STRIDE + c * 8]      = fv;
        *(bf16x8*)&xs[r * X2_STRIDE + 64 + c * 8] = sv;
    }
    __syncthreads();

    const int wave = t >> 6;
    const int lane = t & 63;
    const int m0   = wave * 16;
    const int lrow = lane & 15;
    const int quad = lane >> 4;

    f32x4 acc[4] = {{0,0,0,0},{0,0,0,0},{0,0,0,0},{0,0,0,0}};
    #pragma unroll
    for (int k = 0; k < 4; ++k) {
        const bf16x8 a = *(const bf16x8*)&xs[(m0 + lrow) * X2_STRIDE + k * 32 + quad * 8];
        #pragma unroll
        for (int n = 0; n < 4; ++n) {
            const bf16x8 b = ld8(W3, (size_t)(n * 16 + lrow) * 128 + k * 32 + quad * 8, F32);
            acc[n] = MFMA16(a, b, acc[n]);
        }
    }

    #pragma unroll
    for (int n = 0; n < 4; ++n) {
        const int col  = n * 16 + lrow;
        const float bb = ldf(b3, col, F32);
        #pragma unroll
        for (int r = 0; r < 4; ++r) {
            float v = acc[n][r] + bb;
            v = v > 0.f ? v : 0.f;
            h3s[(m0 + quad * 4 + r) * HS_STRIDE + col] = (bf16)v;
        }
    }
    __syncthreads();

    f32x4 acc2[4] = {{0,0,0,0},{0,0,0,0},{0,0,0,0},{0,0,0,0}};
    #pragma unroll
    for (int k = 0; k < 2; ++k) {
        const bf16x8 a = *(const bf16x8*)&h3s[(m0 + lrow) * HS_STRIDE + k * 32 + quad * 8];
        #pragma unroll
        for (int n = 0; n < 4; ++n) {
            const bf16x8 b = ld8(W4, (size_t)(n * 16 + lrow) * D + k * 32 + quad * 8, F32);
            acc2[n] = MFMA16(a, b, acc2[n]);
        }
    }

    #pragma unroll
    for (int n = 0; n < 4; ++n) {
        const int col  = n * 16 + lrow;
        const float bb = ldf(b4, col, F32);
        #pragma unroll
        for (int r = 0; r < 4; ++r) {
            const int node = r0 + m0 + quad * 4 + r;
            if (node < N_NODES) {
                const float v = acc2[n][r] + bb;
                if (F32) ((float*)out)[(size_t)node * D + col] = v;
                else     ((bf16*)out)[(size_t)node * D + col] = (bf16)v;
            }
        }
    }
}

extern "C" void kernel_launch(void* const* d_in, const int* in_sizes, int n_in,
                              void* d_out, int out_size, void* d_ws, size_t ws_size,
                              hipStream_t stream) {
    const void* feat  = d_in[0];
    const void* eidx  = d_in[1];
    const void* efeat = d_in[2];
    const void* W1    = d_in[3];
    const void* b1    = d_in[4];
    const void* W2    = d_in[5];
    const void* b2    = d_in[6];
    const void* W3    = d_in[7];
    const void* b3    = d_in[8];
    const void* W4    = d_in[9];
    const void* b4    = d_in[10];

    char* ws = (char*)d_ws;

    if (ws_size >= WS_FAST_NEED) {
        bf16* fbuf   = (bf16*)(ws + OFF_FBUF);
        bf16* h2ws   = (bf16*)(ws + OFF_H2);
        int*  eperm  = (int*)(ws + OFF_EPERM);
        int*  rowptr = (int*)(ws + OFF_ROWPTR);
        int*  cursor = (int*)(ws + OFF_CURSOR);
        int*  counts = (int*)(ws + OFF_COUNTS);
        bf16* wbf    = (bf16*)(ws + OFF_WBF);
        int*  flags  = (int*)(ws + OFF_FLAGS);

        detect_kernel<<<1, 64, 0, stream>>>(feat, eidx, flags);
        hipMemsetAsync(counts, 0, (size_t)N_NODES * sizeof(int), stream);
        prep_kernel<<<1, 256, 0, stream>>>(W1, W2, W3, W4, wbf, flags);
        conv_feat_kernel<<<3125, 256, 0, stream>>>(feat, fbuf, flags);
        hist_kernel<<<N_EDGES / 256, 256, 0, stream>>>(eidx, counts, flags);
        scan_kernel<<<1, 256, 0, stream>>>(counts, rowptr, cursor);
        fill_kernel<<<N_EDGES / 256, 256, 0, stream>>>(eidx, cursor, eperm, flags);
        edge_fast<<<N_EDGES / 64, 256, 0, stream>>>(fbuf, eidx, efeat, wbf, b1, b2,
                                                    h2ws, flags);
        node_fast<<<(N_NODES + 63) / 64, 256, 0, stream>>>(fbuf, h2ws, rowptr, eperm,
                                                           wbf, b3, b4, d_out, flags);
    } else {
        float* sbuf  = (float*)(ws + S_SBUF);
        int*   flags = (int*)(ws + S_FLAGS);

        detect_kernel<<<1, 64, 0, stream>>>(feat, eidx, flags);
        hipMemsetAsync(sbuf, 0, (size_t)N_NODES * D * sizeof(float), stream);
        edge_slow<<<N_EDGES / 64, 256, 0, stream>>>(feat, eidx, efeat, W1, b1, W2, b2,
                                                    sbuf, flags);
        node_slow<<<(N_NODES + 63) / 64, 256, 0, stream>>>(feat, sbuf, W3, b3, W4, b4,
                                                           d_out, flags);
    }
}

// Round 3
// 591.853 us; speedup vs baseline: 1.3465x; 1.3465x over previous
//
#include <hip/hip_runtime.h>

typedef __bf16 bf16;
typedef __bf16 bf16x4 __attribute__((ext_vector_type(4)));
typedef __bf16 bf16x8 __attribute__((ext_vector_type(8)));
typedef float  f32x4  __attribute__((ext_vector_type(4)));

#define MFMA16(a, b, c) __builtin_amdgcn_mfma_f32_16x16x32_bf16((a), (b), (c), 0, 0, 0)

constexpr int N_NODES = 50000;
constexpr int N_EDGES = 800000;
constexpr int D = 64;

// ---------------- fast-path workspace layout (~112.7 MB) ----------------
constexpr size_t OFF_FBUF   = 0;                       // bf16[N_NODES*D]   6.4e6 B
constexpr size_t OFF_H2     = 6400000;                 // bf16[N_EDGES*D] 102.4e6 B
constexpr size_t OFF_IPOS   = 108800000;               // int[N_EDGES] (edge -> CSR slot)
constexpr size_t OFF_ROWPTR = 112000000;               // int[N_NODES+1]
constexpr size_t OFF_CURSOR = 112200064;               // int[N_NODES]
constexpr size_t OFF_COUNTS = 112400064;               // int[N_NODES]
constexpr size_t OFF_WBF    = 112600064;               // bf16[28672]
constexpr size_t OFF_FLAGS  = 112657408;               // int[2]
constexpr size_t WS_FAST_NEED = 112700000;

// ---------------- slow-path fallback layout (~12.9 MB) --------------
constexpr size_t S_SBUF  = 0;                          // f32[N_NODES*D] 12.8e6 B
constexpr size_t S_FLAGS = 12800000;

// strides (elements). LDS B-tiles padded so row stride is != 0 mod 32 dwords
// while staying a multiple of 8 elems (16-B alignment for ds_read_b128).
constexpr int XS_STRIDE = 200;
constexpr int HS_STRIDE = 72;
constexpr int X2_STRIDE = 136;
constexpr int W1_STRIDE = 200;   // 192 + 8 pad
constexpr int W2_STRIDE = 72;    // 64 + 8 pad
constexpr int W3_STRIDE = 136;   // 128 + 8 pad
constexpr int W4_STRIDE = 72;    // 64 + 8 pad

// ---------------------------------------------------------------------------
// Dtype detection (proven): flags[0]=1 -> f32 arrays; flags[1]=1 -> i64 idx.
// ---------------------------------------------------------------------------
__global__ void detect_kernel(const void* __restrict__ feat,
                              const void* __restrict__ eidx,
                              int* __restrict__ flags)
{
    __shared__ int c_bf[64], c_nz[64];
    const int t = threadIdx.x;
    const unsigned short* h = (const unsigned short*)feat;
    int c = 0;
    #pragma unroll
    for (int j = 0; j < 8; ++j) {
        const unsigned short v = h[(t * 8 + j) * 2];
        const int e8 = (v >> 7) & 0xFF;
        c += (e8 >= 97 && e8 <= 157) ? 1 : 0;
    }
    c_bf[t] = c;
    const int* ei = (const int*)eidx;
    int nz = 0;
    #pragma unroll
    for (int j = 0; j < 2; ++j)
        nz += (ei[(t * 2 + j) * 2 + 1] != 0) ? 1 : 0;
    c_nz[t] = nz;
    __syncthreads();
    if (t == 0) {
        int s = 0, s2 = 0;
        for (int i = 0; i < 64; ++i) { s += c_bf[i]; s2 += c_nz[i]; }
        flags[0] = (s < 384) ? 1 : 0;
        flags[1] = (s2 < 4) ? 1 : 0;
    }
}

__device__ inline bf16x8 ld8(const void* base, size_t off, int f32f) {
    if (f32f) {
        const float* p = (const float*)base + off;
        const float4 a = *(const float4*)p;
        const float4 b = *(const float4*)(p + 4);
        bf16x8 r;
        r[0] = (bf16)a.x; r[1] = (bf16)a.y; r[2] = (bf16)a.z; r[3] = (bf16)a.w;
        r[4] = (bf16)b.x; r[5] = (bf16)b.y; r[6] = (bf16)b.z; r[7] = (bf16)b.w;
        return r;
    }
    return *(const bf16x8*)((const bf16*)base + off);
}

__device__ inline float ldf(const void* base, int i, int f32f) {
    return f32f ? ((const float*)base)[i] : (float)((const bf16*)base)[i];
}

__device__ inline int gidx(const void* e, size_t i, int i64f) {
    return i64f ? (int)((const long long*)e)[i] : ((const int*)e)[i];
}

// ---------------------------------------------------------------------------
// Weight pre-conversion: wbf = bf16[ W1(12288) | W2(4096) | W3(8192) | W4(4096) ]
// ---------------------------------------------------------------------------
__global__ void prep_kernel(const void* __restrict__ W1, const void* __restrict__ W2,
                            const void* __restrict__ W3, const void* __restrict__ W4,
                            bf16* __restrict__ wbf, const int* __restrict__ flags)
{
    const int F32 = flags[0];
    for (int i = threadIdx.x; i < 28672; i += 256) {
        const void* src; int off;
        if (i < 12288)      { src = W1; off = i; }
        else if (i < 16384) { src = W2; off = i - 12288; }
        else if (i < 24576) { src = W3; off = i - 16384; }
        else                { src = W4; off = i - 24576; }
        wbf[i] = F32 ? (bf16)((const float*)src)[off] : ((const bf16*)src)[off];
    }
}

// feat -> bf16 table (4 elems/thread; grid 3125*256 = 800000 exact)
__global__ void conv_feat_kernel(const void* __restrict__ feat, bf16* __restrict__ fbuf,
                                 const int* __restrict__ flags)
{
    const int F32 = flags[0];
    const int i = blockIdx.x * 256 + threadIdx.x;     // 0..799999 (x4 elems)
    if (F32) {
        const float4 v = ((const float4*)feat)[i];
        bf16x4 r; r[0] = (bf16)v.x; r[1] = (bf16)v.y; r[2] = (bf16)v.z; r[3] = (bf16)v.w;
        ((bf16x4*)fbuf)[i] = r;
    } else {
        ((bf16x4*)fbuf)[i] = ((const bf16x4*)feat)[i];
    }
}

// ---------------------------------------------------------------------------
// CSR build: histogram -> scan -> slot assignment (ipos[e] = CSR slot).
// R3: edge writes h2 scattered at ipos (A/B-proven FREE: 253.5 vs 253.2 us);
// node reads h2 contiguously (streaming). scan vectorized with int4 (it was
// a serial-latency chain: 196 dependent scalar loads/thread).
// ---------------------------------------------------------------------------
__global__ void hist_kernel(const void* __restrict__ eidx, int* __restrict__ counts,
                            const int* __restrict__ flags)
{
    const int I64 = flags[1];
    const int e = blockIdx.x * 256 + threadIdx.x;
    atomicAdd(&counts[gidx(eidx, e, I64)], 1);
}

__global__ void scan_kernel(const int* __restrict__ counts, int* __restrict__ rowptr,
                            int* __restrict__ cursor)
{
    __shared__ int part[256];
    const int t = threadIdx.x;
    const int base = t * 196;            // 196*4B = 784B, 16B-aligned; 50000%4==0
    int s = 0;
    for (int g = 0; g < 49; ++g) {
        const int idx = base + g * 4;
        if (idx < N_NODES) {
            const int4 v = *(const int4*)&counts[idx];
            s += v.x + v.y + v.z + v.w;
        }
    }
    part[t] = s;
    __syncthreads();
    if (t == 0) {
        int acc = 0;
        for (int i = 0; i < 256; ++i) { const int v = part[i]; part[i] = acc; acc += v; }
        rowptr[N_NODES] = acc;
    }
    __syncthreads();
    int acc = part[t];
    for (int g = 0; g < 49; ++g) {
        const int idx = base + g * 4;
        if (idx < N_NODES) {
            const int4 v = *(const int4*)&counts[idx];
            int4 r;
            r.x = acc;
            r.y = acc + v.x;
            r.z = acc + v.x + v.y;
            r.w = acc + v.x + v.y + v.z;
            acc += v.x + v.y + v.z + v.w;
            *(int4*)&rowptr[idx] = r;
            *(int4*)&cursor[idx] = r;
        }
    }
}

__global__ void fill_kernel(const void* __restrict__ eidx, int* __restrict__ cursor,
                            int* __restrict__ ipos, const int* __restrict__ flags)
{
    const int I64 = flags[1];
    const int e = blockIdx.x * 256 + threadIdx.x;
    const int src = gidx(eidx, e, I64);
    ipos[e] = atomicAdd(&cursor[src], 1);   // edge -> CSR slot
}

// ---------------------------------------------------------------------------
// FAST edge kernel (R3): W1/W2 staged to LDS once per block. B-fragments come
// from ds_read (no VMEM/TA round trips) -- the per-wave serialized global
// W-gathers were the latency bottleneck (all pipes idle at 253us, VGPR=40).
// One wave = 16 edges; h2 rows -> h2ws[ipos[e]] (scattered stores: proven free).
// hs doubles as h2-store staging (wave-private, program-ordered).
// ---------------------------------------------------------------------------
__global__ __launch_bounds__(256) void edge_fast(
    const bf16* __restrict__ fbuf, const void* __restrict__ eidx,
    const void* __restrict__ efeat,
    const bf16* __restrict__ wbf, const void* __restrict__ b1, const void* __restrict__ b2,
    const int* __restrict__ ipos, bf16* __restrict__ h2ws, const int* __restrict__ flags)
{
    __shared__ bf16 W1l[64 * W1_STRIDE];   // 25600 B
    __shared__ bf16 W2l[64 * W2_STRIDE];   //  9216 B
    __shared__ bf16 hs[4][16 * 72];        //  9216 B (h1 roundtrip + store staging)

    const int t    = threadIdx.x;
    const int wave = t >> 6;
    const int lane = t & 63;
    const int lrow = lane & 15;
    const int quad = lane >> 4;
    const int e0   = blockIdx.x * 64 + wave * 16;   // this wave's 16 edges
    const int F32  = flags[0], I64 = flags[1];

    // ---- stage W1 (12288 elems) + W2 (4096 elems) into LDS, bf16x8 chunks ----
    #pragma unroll
    for (int it = 0; it < 6; ++it) {
        const int idx = it * 256 + t;           // 0..1535
        const int row = idx / 24;               // 192/8 = 24 chunks per row
        const int col = (idx - row * 24) * 8;
        *(bf16x8*)&W1l[row * W1_STRIDE + col] = *(const bf16x8*)&wbf[row * 192 + col];
    }
    #pragma unroll
    for (int it = 0; it < 2; ++it) {
        const int idx = it * 256 + t;           // 0..511
        const int row = idx >> 3;               // 64/8 = 8 chunks per row
        const int col = (idx & 7) * 8;
        *(bf16x8*)&W2l[row * W2_STRIDE + col] = *(const bf16x8*)&wbf[12288 + row * 64 + col];
    }
    __syncthreads();

    const int e   = e0 + lrow;
    const int src = gidx(eidx, (size_t)e, I64);
    const int dst = gidx(eidx, (size_t)N_EDGES + e, I64);

    // GEMM1: K=192. A row = [fbuf[src] | efeat[e] | fbuf[dst]]; part = k>>1.
    f32x4 acc[4] = {{0,0,0,0},{0,0,0,0},{0,0,0,0},{0,0,0,0}};
    #pragma unroll
    for (int k = 0; k < 6; ++k) {
        const int po = (k & 1) * 32 + quad * 8;     // offset within the 64-elem part
        bf16x8 a;
        if (k < 2)      a = *(const bf16x8*)&fbuf[(size_t)src * D + po];
        else if (k < 4) a = ld8(efeat, (size_t)e * D + po, F32);
        else            a = *(const bf16x8*)&fbuf[(size_t)dst * D + po];
        #pragma unroll
        for (int n = 0; n < 4; ++n) {
            const bf16x8 b = *(const bf16x8*)&W1l[(n * 16 + lrow) * W1_STRIDE + k * 32 + quad * 8];
            acc[n] = MFMA16(a, b, acc[n]);
        }
    }

    // ReLU + b1; C-layout -> wave-private LDS (A-layout for GEMM2). No barrier.
    #pragma unroll
    for (int n = 0; n < 4; ++n) {
        const int col  = n * 16 + lrow;
        const float bb = ldf(b1, col, F32);
        #pragma unroll
        for (int r = 0; r < 4; ++r) {
            float v = acc[n][r] + bb;
            v = v > 0.f ? v : 0.f;
            hs[wave][(quad * 4 + r) * 72 + col] = (bf16)v;
        }
    }

    // GEMM2: K=64.
    f32x4 acc2[4] = {{0,0,0,0},{0,0,0,0},{0,0,0,0},{0,0,0,0}};
    #pragma unroll
    for (int k = 0; k < 2; ++k) {
        const bf16x8 a = *(const bf16x8*)&hs[wave][lrow * 72 + k * 32 + quad * 8];
        #pragma unroll
        for (int n = 0; n < 4; ++n) {
            const bf16x8 b = *(const bf16x8*)&W2l[(n * 16 + lrow) * W2_STRIDE + k * 32 + quad * 8];
            acc2[n] = MFMA16(a, b, acc2[n]);
        }
    }

    // h2 + b2 -> hs (reused; all hs reads done), then 32B/lane scattered store.
    #pragma unroll
    for (int n = 0; n < 4; ++n) {
        const int col  = n * 16 + lrow;
        const float bb = ldf(b2, col, F32);
        #pragma unroll
        for (int r = 0; r < 4; ++r)
            hs[wave][(quad * 4 + r) * 72 + col] = (bf16)(acc2[n][r] + bb);
    }

    const int row = lane >> 2;          // 0..15 (edge row within wave)
    const int seg = lane & 3;           // 16-col segment
    const int ip  = ipos[e0 + row];
    const bf16x8 v0 = *(const bf16x8*)&hs[wave][row * 72 + seg * 16];
    const bf16x8 v1 = *(const bf16x8*)&hs[wave][row * 72 + seg * 16 + 8];
    *(bf16x8*)&h2ws[(size_t)ip * D + seg * 16]     = v0;
    *(bf16x8*)&h2ws[(size_t)ip * D + seg * 16 + 8] = v1;
}

// ---------------------------------------------------------------------------
// FAST node kernel (R3): contiguous CSR segment-sum of h2ws (streaming reads),
// W3/W4 staged to LDS once per block (same latency fix as edge).
// 64 nodes/block; gather: 4 lanes per node, 16 cols each.
// ---------------------------------------------------------------------------
__global__ __launch_bounds__(256) void node_fast(
    const bf16* __restrict__ fbuf, const bf16* __restrict__ h2ws,
    const int* __restrict__ rowptr,
    const bf16* __restrict__ wbf, const void* __restrict__ b3, const void* __restrict__ b4,
    void* __restrict__ out, const int* __restrict__ flags)
{
    __shared__ bf16 xs[64 * X2_STRIDE];    // 17408 B
    __shared__ bf16 h3s[64 * HS_STRIDE];   //  9216 B
    __shared__ bf16 W3l[64 * W3_STRIDE];   // 17408 B
    __shared__ bf16 W4l[64 * W4_STRIDE];   //  9216 B

    const int t  = threadIdx.x;
    const int r0 = blockIdx.x * 64;
    const int F32 = flags[0];

    // ---- stage W3 (8192 elems) + W4 (4096 elems) ----
    #pragma unroll
    for (int it = 0; it < 4; ++it) {
        const int idx = it * 256 + t;           // 0..1023
        const int row = idx >> 4;               // 128/8 = 16 chunks per row
        const int col = (idx & 15) * 8;
        *(bf16x8*)&W3l[row * W3_STRIDE + col] = *(const bf16x8*)&wbf[16384 + row * 128 + col];
    }
    #pragma unroll
    for (int it = 0; it < 2; ++it) {
        const int idx = it * 256 + t;           // 0..511
        const int row = idx >> 3;
        const int col = (idx & 7) * 8;
        *(bf16x8*)&W4l[row * W4_STRIDE + col] = *(const bf16x8*)&wbf[24576 + row * 64 + col];
    }

    // segment sum: thread t -> node r0 + (t>>2), col segment (t&3)*16
    {
        const int nloc = t >> 2;
        const int node = r0 + nloc;
        const int seg  = t & 3;
        float accv[16];
        #pragma unroll
        for (int i = 0; i < 16; ++i) accv[i] = 0.f;
        bf16x8 f0 = {0,0,0,0,0,0,0,0}, f1 = {0,0,0,0,0,0,0,0};
        if (node < N_NODES) {
            f0 = *(const bf16x8*)&fbuf[(size_t)node * D + seg * 16];
            f1 = *(const bf16x8*)&fbuf[(size_t)node * D + seg * 16 + 8];
            const int jb = rowptr[node], je = rowptr[node + 1];
            int j = jb;
            for (; j + 4 <= je; j += 4) {
                const bf16x8 a0 = *(const bf16x8*)&h2ws[(size_t)j * D + seg * 16];
                const bf16x8 a1 = *(const bf16x8*)&h2ws[(size_t)j * D + seg * 16 + 8];
                const bf16x8 b0 = *(const bf16x8*)&h2ws[(size_t)(j + 1) * D + seg * 16];
                const bf16x8 b1v = *(const bf16x8*)&h2ws[(size_t)(j + 1) * D + seg * 16 + 8];
                const bf16x8 c0 = *(const bf16x8*)&h2ws[(size_t)(j + 2) * D + seg * 16];
                const bf16x8 c1 = *(const bf16x8*)&h2ws[(size_t)(j + 2) * D + seg * 16 + 8];
                const bf16x8 d0 = *(const bf16x8*)&h2ws[(size_t)(j + 3) * D + seg * 16];
                const bf16x8 d1 = *(const bf16x8*)&h2ws[(size_t)(j + 3) * D + seg * 16 + 8];
                #pragma unroll
                for (int i = 0; i < 8; ++i) {
                    accv[i]     += ((float)a0[i] + (float)b0[i]) + ((float)c0[i] + (float)d0[i]);
                    accv[i + 8] += ((float)a1[i] + (float)b1v[i]) + ((float)c1[i] + (float)d1[i]);
                }
            }
            for (; j < je; ++j) {
                const bf16x8 a0 = *(const bf16x8*)&h2ws[(size_t)j * D + seg * 16];
                const bf16x8 a1 = *(const bf16x8*)&h2ws[(size_t)j * D + seg * 16 + 8];
                #pragma unroll
                for (int i = 0; i < 8; ++i) {
                    accv[i]     += (float)a0[i];
                    accv[i + 8] += (float)a1[i];
                }
            }
        }
        bf16x8 s0, s1;
        #pragma unroll
        for (int i = 0; i < 8; ++i) {
            s0[i] = (bf16)((float)f0[i] + accv[i]);
            s1[i] = (bf16)((float)f1[i] + accv[i + 8]);
        }
        *(bf16x8*)&xs[nloc * X2_STRIDE + seg * 16]          = f0;
        *(bf16x8*)&xs[nloc * X2_STRIDE + seg * 16 + 8]      = f1;
        *(bf16x8*)&xs[nloc * X2_STRIDE + 64 + seg * 16]     = s0;
        *(bf16x8*)&xs[nloc * X2_STRIDE + 64 + seg * 16 + 8] = s1;
    }
    __syncthreads();

    const int wave = t >> 6;
    const int lane = t & 63;
    const int m0   = wave * 16;
    const int lrow = lane & 15;
    const int quad = lane >> 4;

    // GEMM3: K=128
    f32x4 acc[4] = {{0,0,0,0},{0,0,0,0},{0,0,0,0},{0,0,0,0}};
    #pragma unroll
    for (int k = 0; k < 4; ++k) {
        const bf16x8 a = *(const bf16x8*)&xs[(m0 + lrow) * X2_STRIDE + k * 32 + quad * 8];
        #pragma unroll
        for (int n = 0; n < 4; ++n) {
            const bf16x8 b = *(const bf16x8*)&W3l[(n * 16 + lrow) * W3_STRIDE + k * 32 + quad * 8];
            acc[n] = MFMA16(a, b, acc[n]);
        }
    }

    #pragma unroll
    for (int n = 0; n < 4; ++n) {
        const int col  = n * 16 + lrow;
        const float bb = ldf(b3, col, F32);
        #pragma unroll
        for (int r = 0; r < 4; ++r) {
            float v = acc[n][r] + bb;
            v = v > 0.f ? v : 0.f;
            h3s[(m0 + quad * 4 + r) * HS_STRIDE + col] = (bf16)v;
        }
    }

    // GEMM4: K=64 (h3s rows are wave-private; no barrier needed)
    f32x4 acc2[4] = {{0,0,0,0},{0,0,0,0},{0,0,0,0},{0,0,0,0}};
    #pragma unroll
    for (int k = 0; k < 2; ++k) {
        const bf16x8 a = *(const bf16x8*)&h3s[(m0 + lrow) * HS_STRIDE + k * 32 + quad * 8];
        #pragma unroll
        for (int n = 0; n < 4; ++n) {
            const bf16x8 b = *(const bf16x8*)&W4l[(n * 16 + lrow) * W4_STRIDE + k * 32 + quad * 8];
            acc2[n] = MFMA16(a, b, acc2[n]);
        }
    }

    #pragma unroll
    for (int n = 0; n < 4; ++n) {
        const int col  = n * 16 + lrow;
        const float bb = ldf(b4, col, F32);
        #pragma unroll
        for (int r = 0; r < 4; ++r) {
            const int node = r0 + m0 + quad * 4 + r;
            if (node < N_NODES) {
                const float v = acc2[n][r] + bb;
                if (F32) ((float*)out)[(size_t)node * D + col] = v;
                else     ((bf16*)out)[(size_t)node * D + col] = (bf16)v;
            }
        }
    }
}

// ---------------------------------------------------------------------------
// SLOW fallback = proven R2 kernels (global f32 atomic scatter), used only
// if ws_size is too small for the fast path.
// ---------------------------------------------------------------------------
__global__ __launch_bounds__(256) void edge_slow(
    const void* __restrict__ feat, const void* __restrict__ eidx,
    const void* __restrict__ efeat,
    const void* __restrict__ W1, const void* __restrict__ b1,
    const void* __restrict__ W2, const void* __restrict__ b2,
    float* __restrict__ sbuf, const int* __restrict__ flags)
{
    __shared__ bf16 xs[64 * XS_STRIDE];
    __shared__ bf16 h1s[64 * HS_STRIDE];
    __shared__ int  srcs[64];
    __shared__ int  fl[2];

    const int t  = threadIdx.x;
    const int e0 = blockIdx.x * 64;

    if (t < 2) fl[t] = flags[t];
    __syncthreads();
    const int F32 = fl[0], I64 = fl[1];

    if (t < 64) srcs[t] = gidx(eidx, e0 + t, I64);

    for (int i = t; i < 64 * 24; i += 256) {
        const int e    = i / 24;
        const int c    = i - e * 24;
        const int part = c >> 3;
        const int cc   = c & 7;
        size_t off;
        const void* base;
        if (part == 0)      { base = feat;  off = (size_t)gidx(eidx, e0 + e, I64) * D + cc * 8; }
        else if (part == 1) { base = efeat; off = (size_t)(e0 + e) * D + cc * 8; }
        else                { base = feat;  off = (size_t)gidx(eidx, (size_t)N_EDGES + e0 + e, I64) * D + cc * 8; }
        *(bf16x8*)&xs[e * XS_STRIDE + part * 64 + cc * 8] = ld8(base, off, F32);
    }
    __syncthreads();

    const int wave = t >> 6;
    const int lane = t & 63;
    const int m0   = wave * 16;
    const int lrow = lane & 15;
    const int quad = lane >> 4;

    f32x4 acc[4] = {{0,0,0,0},{0,0,0,0},{0,0,0,0},{0,0,0,0}};
    #pragma unroll
    for (int k = 0; k < 6; ++k) {
        const bf16x8 a = *(const bf16x8*)&xs[(m0 + lrow) * XS_STRIDE + k * 32 + quad * 8];
        #pragma unroll
        for (int n = 0; n < 4; ++n) {
            const bf16x8 b = ld8(W1, (size_t)(n * 16 + lrow) * 192 + k * 32 + quad * 8, F32);
            acc[n] = MFMA16(a, b, acc[n]);
        }
    }

    #pragma unroll
    for (int n = 0; n < 4; ++n) {
        const int col  = n * 16 + lrow;
        const float bb = ldf(b1, col, F32);
        #pragma unroll
        for (int r = 0; r < 4; ++r) {
            float v = acc[n][r] + bb;
            v = v > 0.f ? v : 0.f;
            h1s[(m0 + quad * 4 + r) * HS_STRIDE + col] = (bf16)v;
        }
    }
    __syncthreads();

    f32x4 acc2[4] = {{0,0,0,0},{0,0,0,0},{0,0,0,0},{0,0,0,0}};
    #pragma unroll
    for (int k = 0; k < 2; ++k) {
        const bf16x8 a = *(const bf16x8*)&h1s[(m0 + lrow) * HS_STRIDE + k * 32 + quad * 8];
        #pragma unroll
        for (int n = 0; n < 4; ++n) {
            const bf16x8 b = ld8(W2, (size_t)(n * 16 + lrow) * D + k * 32 + quad * 8, F32);
            acc2[n] = MFMA16(a, b, acc2[n]);
        }
    }

    #pragma unroll
    for (int n = 0; n < 4; ++n) {
        const int col  = n * 16 + lrow;
        const float bb = ldf(b2, col, F32);
        #pragma unroll
        for (int r = 0; r < 4; ++r) {
            const int e = m0 + quad * 4 + r;
            atomicAdd(&sbuf[(size_t)srcs[e] * D + col], acc2[n][r] + bb);
        }
    }
}

__global__ __launch_bounds__(256) void node_slow(
    const void* __restrict__ feat, const float* __restrict__ sbuf,
    const void* __restrict__ W3, const void* __restrict__ b3,
    const void* __restrict__ W4, const void* __restrict__ b4,
    void* __restrict__ out, const int* __restrict__ flags)
{
    __shared__ bf16 xs[64 * X2_STRIDE];
    __shared__ bf16 h3s[64 * HS_STRIDE];
    __shared__ int fl[1];

    const int t  = threadIdx.x;
    const int r0 = blockIdx.x * 64;

    if (t == 0) fl[0] = flags[0];
    __syncthreads();
    const int F32 = fl[0];

    for (int i = t; i < 64 * 8; i += 256) {
        const int r    = i >> 3;
        const int c    = i & 7;
        const int node = r0 + r;
        bf16x8 fv = {0,0,0,0,0,0,0,0};
        bf16x8 sv = {0,0,0,0,0,0,0,0};
        if (node < N_NODES) {
            fv = ld8(feat, (size_t)node * D + c * 8, F32);
            const float4 sa = *(const float4*)&sbuf[(size_t)node * D + c * 8];
            const float4 sb = *(const float4*)&sbuf[(size_t)node * D + c * 8 + 4];
            sv[0] = (bf16)((float)fv[0] + sa.x);
            sv[1] = (bf16)((float)fv[1] + sa.y);
            sv[2] = (bf16)((float)fv[2] + sa.z);
            sv[3] = (bf16)((float)fv[3] + sa.w);
            sv[4] = (bf16)((float)fv[4] + sb.x);
            sv[5] = (bf16)((float)fv[5] + sb.y);
            sv[6] = (bf16)((float)fv[6] + sb.z);
            sv[7] = (bf16)((float)fv[7] + sb.w);
        }
        *(bf16x8*)&xs[r * X2_STRIDE + c * 8]      = fv;
        *(bf16x8*)&xs[r * X2_STRIDE + 64 + c * 8] = sv;
    }
    __syncthreads();

    const int wave = t >> 6;
    const int lane = t & 63;
    const int m0   = wave * 16;
    const int lrow = lane & 15;
    const int quad = lane >> 4;

    f32x4 acc[4] = {{0,0,0,0},{0,0,0,0},{0,0,0,0},{0,0,0,0}};
    #pragma unroll
    for (int k = 0; k < 4; ++k) {
        const bf16x8 a = *(const bf16x8*)&xs[(m0 + lrow) * X2_STRIDE + k * 32 + quad * 8];
        #pragma unroll
        for (int n = 0; n < 4; ++n) {
            const bf16x8 b = ld8(W3, (size_t)(n * 16 + lrow) * 128 + k * 32 + quad * 8, F32);
            acc[n] = MFMA16(a, b, acc[n]);
        }
    }

    #pragma unroll
    for (int n = 0; n < 4; ++n) {
        const int col  = n * 16 + lrow;
        const float bb = ldf(b3, col, F32);
        #pragma unroll
        for (int r = 0; r < 4; ++r) {
            float v = acc[n][r] + bb;
            v = v > 0.f ? v : 0.f;
            h3s[(m0 + quad * 4 + r) * HS_STRIDE + col] = (bf16)v;
        }
    }
    __syncthreads();

    f32x4 acc2[4] = {{0,0,0,0},{0,0,0,0},{0,0,0,0},{0,0,0,0}};
    #pragma unroll
    for (int k = 0; k < 2; ++k) {
        const bf16x8 a = *(const bf16x8*)&h3s[(m0 + lrow) * HS_STRIDE + k * 32 + quad * 8];
        #pragma unroll
        for (int n = 0; n < 4; ++n) {
            const bf16x8 b = ld8(W4, (size_t)(n * 16 + lrow) * D + k * 32 + quad * 8, F32);
            acc2[n] = MFMA16(a, b, acc2[n]);
        }
    }

    #pragma unroll
    for (int n = 0; n < 4; ++n) {
        const int col  = n * 16 + lrow;
        const float bb = ldf(b4, col, F32);
        #pragma unroll
        for (int r = 0; r < 4; ++r) {
            const int node = r0 + m0 + quad * 4 + r;
            if (node < N_NODES) {
                const float v = acc2[n][r] + bb;
                if (F32) ((float*)out)[(size_t)node * D + col] = v;
                else     ((bf16*)out)[(size_t)node * D + col] = (bf16)v;
            }
        }
    }
}

extern "C" void kernel_launch(void* const* d_in, const int* in_sizes, int n_in,
                              void* d_out, int out_size, void* d_ws, size_t ws_size,
                              hipStream_t stream) {
    const void* feat  = d_in[0];
    const void* eidx  = d_in[1];
    const void* efeat = d_in[2];
    const void* W1    = d_in[3];
    const void* b1    = d_in[4];
    const void* W2    = d_in[5];
    const void* b2    = d_in[6];
    const void* W3    = d_in[7];
    const void* b3    = d_in[8];
    const void* W4    = d_in[9];
    const void* b4    = d_in[10];

    char* ws = (char*)d_ws;

    if (ws_size >= WS_FAST_NEED) {
        bf16* fbuf   = (bf16*)(ws + OFF_FBUF);
        bf16* h2ws   = (bf16*)(ws + OFF_H2);
        int*  ipos   = (int*)(ws + OFF_IPOS);
        int*  rowptr = (int*)(ws + OFF_ROWPTR);
        int*  cursor = (int*)(ws + OFF_CURSOR);
        int*  counts = (int*)(ws + OFF_COUNTS);
        bf16* wbf    = (bf16*)(ws + OFF_WBF);
        int*  flags  = (int*)(ws + OFF_FLAGS);

        detect_kernel<<<1, 64, 0, stream>>>(feat, eidx, flags);
        hipMemsetAsync(counts, 0, (size_t)N_NODES * sizeof(int), stream);
        prep_kernel<<<1, 256, 0, stream>>>(W1, W2, W3, W4, wbf, flags);
        conv_feat_kernel<<<3125, 256, 0, stream>>>(feat, fbuf, flags);
        hist_kernel<<<N_EDGES / 256, 256, 0, stream>>>(eidx, counts, flags);
        scan_kernel<<<1, 256, 0, stream>>>(counts, rowptr, cursor);
        fill_kernel<<<N_EDGES / 256, 256, 0, stream>>>(eidx, cursor, ipos, flags);
        edge_fast<<<N_EDGES / 64, 256, 0, stream>>>(fbuf, eidx, efeat, wbf, b1, b2,
                                                    ipos, h2ws, flags);
        node_fast<<<(N_NODES + 63) / 64, 256, 0, stream>>>(fbuf, h2ws, rowptr,
                                                           wbf, b3, b4, d_out, flags);
    } else {
        float* sbuf  = (float*)(ws + S_SBUF);
        int*   flags = (int*)(ws + S_FLAGS);

        detect_kernel<<<1, 64, 0, stream>>>(feat, eidx, flags);
        hipMemsetAsync(sbuf, 0, (size_t)N_NODES * D * sizeof(float), stream);
        edge_slow<<<N_EDGES / 64, 256, 0, stream>>>(feat, eidx, efeat, W1, b1, W2, b2,
                                                    sbuf, flags);
        node_slow<<<(N_NODES + 63) / 64, 256, 0, stream>>>(feat, sbuf, W3, b3, W4, b4,
                                                           d_out, flags);
    }
}

// Round 4
// 567.781 us; speedup vs baseline: 1.4036x; 1.0424x over previous
//
#include <hip/hip_runtime.h>

typedef __bf16 bf16;
typedef __bf16 bf16x4 __attribute__((ext_vector_type(4)));
typedef __bf16 bf16x8 __attribute__((ext_vector_type(8)));
typedef float  f32x4  __attribute__((ext_vector_type(4)));

#define MFMA16(a, b, c) __builtin_amdgcn_mfma_f32_16x16x32_bf16((a), (b), (c), 0, 0, 0)

constexpr int N_NODES = 50000;
constexpr int N_EDGES = 800000;
constexpr int D = 64;

// ---------------- fast-path workspace layout (~112.7 MB) ----------------
constexpr size_t OFF_FBUF   = 0;                       // bf16[N_NODES*D]   6.4e6 B
constexpr size_t OFF_H2     = 6400000;                 // bf16[N_EDGES*D] 102.4e6 B
constexpr size_t OFF_IPOS   = 108800000;               // int[N_EDGES] (edge -> CSR slot)
constexpr size_t OFF_ROWPTR = 112000000;               // int[N_NODES+1]
constexpr size_t OFF_CURSOR = 112200064;               // int[N_NODES]
constexpr size_t OFF_COUNTS = 112400064;               // int[N_NODES]
constexpr size_t OFF_WBF    = 112600064;               // bf16[28672]
constexpr size_t OFF_FLAGS  = 112657408;               // int[2]
constexpr size_t WS_FAST_NEED = 112700000;

// ---------------- slow-path fallback layout (~12.9 MB) --------------
constexpr size_t S_SBUF  = 0;                          // f32[N_NODES*D] 12.8e6 B
constexpr size_t S_FLAGS = 12800000;

// strides (elements). LDS B-tiles padded: multiple of 8 elems (16B align for
// ds_read_b128), not a multiple of 128 (avoids severe bank alias).
constexpr int XS_STRIDE = 200;
constexpr int HS_STRIDE = 72;
constexpr int X2_STRIDE = 136;
constexpr int W1_STRIDE = 200;   // 192 + 8 pad
constexpr int W2_STRIDE = 72;    // 64 + 8 pad
constexpr int W3_STRIDE = 136;   // 128 + 8 pad
constexpr int W4_STRIDE = 72;    // 64 + 8 pad

// ---------------------------------------------------------------------------
// Dtype detection (proven): flags[0]=1 -> f32 arrays; flags[1]=1 -> i64 idx.
// ---------------------------------------------------------------------------
__global__ void detect_kernel(const void* __restrict__ feat,
                              const void* __restrict__ eidx,
                              int* __restrict__ flags)
{
    __shared__ int c_bf[64], c_nz[64];
    const int t = threadIdx.x;
    const unsigned short* h = (const unsigned short*)feat;
    int c = 0;
    #pragma unroll
    for (int j = 0; j < 8; ++j) {
        const unsigned short v = h[(t * 8 + j) * 2];
        const int e8 = (v >> 7) & 0xFF;
        c += (e8 >= 97 && e8 <= 157) ? 1 : 0;
    }
    c_bf[t] = c;
    const int* ei = (const int*)eidx;
    int nz = 0;
    #pragma unroll
    for (int j = 0; j < 2; ++j)
        nz += (ei[(t * 2 + j) * 2 + 1] != 0) ? 1 : 0;
    c_nz[t] = nz;
    __syncthreads();
    if (t == 0) {
        int s = 0, s2 = 0;
        for (int i = 0; i < 64; ++i) { s += c_bf[i]; s2 += c_nz[i]; }
        flags[0] = (s < 384) ? 1 : 0;
        flags[1] = (s2 < 4) ? 1 : 0;
    }
}

__device__ inline bf16x8 ld8(const void* base, size_t off, int f32f) {
    if (f32f) {
        const float* p = (const float*)base + off;
        const float4 a = *(const float4*)p;
        const float4 b = *(const float4*)(p + 4);
        bf16x8 r;
        r[0] = (bf16)a.x; r[1] = (bf16)a.y; r[2] = (bf16)a.z; r[3] = (bf16)a.w;
        r[4] = (bf16)b.x; r[5] = (bf16)b.y; r[6] = (bf16)b.z; r[7] = (bf16)b.w;
        return r;
    }
    return *(const bf16x8*)((const bf16*)base + off);
}

__device__ inline float ldf(const void* base, int i, int f32f) {
    return f32f ? ((const float*)base)[i] : (float)((const bf16*)base)[i];
}

__device__ inline int gidx(const void* e, size_t i, int i64f) {
    return i64f ? (int)((const long long*)e)[i] : ((const int*)e)[i];
}

// ---------------------------------------------------------------------------
// Weight pre-conversion: wbf = bf16[ W1(12288) | W2(4096) | W3(8192) | W4(4096) ]
// ---------------------------------------------------------------------------
__global__ void prep_kernel(const void* __restrict__ W1, const void* __restrict__ W2,
                            const void* __restrict__ W3, const void* __restrict__ W4,
                            bf16* __restrict__ wbf, const int* __restrict__ flags)
{
    const int F32 = flags[0];
    for (int i = threadIdx.x; i < 28672; i += 256) {
        const void* src; int off;
        if (i < 12288)      { src = W1; off = i; }
        else if (i < 16384) { src = W2; off = i - 12288; }
        else if (i < 24576) { src = W3; off = i - 16384; }
        else                { src = W4; off = i - 24576; }
        wbf[i] = F32 ? (bf16)((const float*)src)[off] : ((const bf16*)src)[off];
    }
}

// feat -> bf16 table (4 elems/thread; grid 3125*256 = 800000 exact)
__global__ void conv_feat_kernel(const void* __restrict__ feat, bf16* __restrict__ fbuf,
                                 const int* __restrict__ flags)
{
    const int F32 = flags[0];
    const int i = blockIdx.x * 256 + threadIdx.x;     // 0..799999 (x4 elems)
    if (F32) {
        const float4 v = ((const float4*)feat)[i];
        bf16x4 r; r[0] = (bf16)v.x; r[1] = (bf16)v.y; r[2] = (bf16)v.z; r[3] = (bf16)v.w;
        ((bf16x4*)fbuf)[i] = r;
    } else {
        ((bf16x4*)fbuf)[i] = ((const bf16x4*)feat)[i];
    }
}

// ---------------------------------------------------------------------------
// CSR build: histogram -> scan -> slot assignment (ipos[e] = CSR slot).
// Edge writes h2 scattered at ipos (A/B-proven FREE); node reads h2
// contiguously (streaming).
// ---------------------------------------------------------------------------
__global__ void hist_kernel(const void* __restrict__ eidx, int* __restrict__ counts,
                            const int* __restrict__ flags)
{
    const int I64 = flags[1];
    const int e = blockIdx.x * 256 + threadIdx.x;
    atomicAdd(&counts[gidx(eidx, e, I64)], 1);
}

__global__ void scan_kernel(const int* __restrict__ counts, int* __restrict__ rowptr,
                            int* __restrict__ cursor)
{
    __shared__ int part[256];
    const int t = threadIdx.x;
    const int base = t * 196;            // 196*4B = 784B, 16B-aligned; 50000%4==0
    int s = 0;
    for (int g = 0; g < 49; ++g) {
        const int idx = base + g * 4;
        if (idx < N_NODES) {
            const int4 v = *(const int4*)&counts[idx];
            s += v.x + v.y + v.z + v.w;
        }
    }
    part[t] = s;
    __syncthreads();
    if (t == 0) {
        int acc = 0;
        for (int i = 0; i < 256; ++i) { const int v = part[i]; part[i] = acc; acc += v; }
        rowptr[N_NODES] = acc;
    }
    __syncthreads();
    int acc = part[t];
    for (int g = 0; g < 49; ++g) {
        const int idx = base + g * 4;
        if (idx < N_NODES) {
            const int4 v = *(const int4*)&counts[idx];
            int4 r;
            r.x = acc;
            r.y = acc + v.x;
            r.z = acc + v.x + v.y;
            r.w = acc + v.x + v.y + v.z;
            acc += v.x + v.y + v.z + v.w;
            *(int4*)&rowptr[idx] = r;
            *(int4*)&cursor[idx] = r;
        }
    }
}

__global__ void fill_kernel(const void* __restrict__ eidx, int* __restrict__ cursor,
                            int* __restrict__ ipos, const int* __restrict__ flags)
{
    const int I64 = flags[1];
    const int e = blockIdx.x * 256 + threadIdx.x;
    const int src = gidx(eidx, e, I64);
    ipos[e] = atomicAdd(&cursor[src], 1);   // edge -> CSR slot
}

// ---------------------------------------------------------------------------
// FAST edge kernel (R4): 32 edges per wave (2 M-tiles register-blocked).
// Each B-fragment ds_read feeds 2 MFMAs; 2x the independent A-gathers in
// flight; 2x MFMA density per wave -- all at unchanged occupancy (LDS 53.2KB
// -> still 3 blocks/CU; __launch_bounds__(256,3) pins VGPR<=170).
// W1/W2 staged in LDS (R3 win). h2 -> h2ws[ipos[e]] (scattered, proven free).
// hs = 32 rows/wave: GEMM1-C->GEMM2-A roundtrip, then reused as store staging.
// ---------------------------------------------------------------------------
__global__ __launch_bounds__(256, 3) void edge_fast(
    const bf16* __restrict__ fbuf, const void* __restrict__ eidx,
    const void* __restrict__ efeat,
    const bf16* __restrict__ wbf, const void* __restrict__ b1, const void* __restrict__ b2,
    const int* __restrict__ ipos, bf16* __restrict__ h2ws, const int* __restrict__ flags)
{
    __shared__ bf16 W1l[64 * W1_STRIDE];   // 25600 B
    __shared__ bf16 W2l[64 * W2_STRIDE];   //  9216 B
    __shared__ bf16 hs[4][32 * 72];        // 18432 B (2 M-tiles per wave)

    const int t    = threadIdx.x;
    const int wave = t >> 6;
    const int lane = t & 63;
    const int lrow = lane & 15;
    const int quad = lane >> 4;
    const int e0   = blockIdx.x * 128 + wave * 32;   // this wave's 32 edges
    const int F32  = flags[0], I64 = flags[1];

    // ---- stage W1 (12288 elems) + W2 (4096 elems) into LDS, bf16x8 chunks ----
    #pragma unroll
    for (int it = 0; it < 6; ++it) {
        const int idx = it * 256 + t;           // 0..1535
        const int row = idx / 24;               // 192/8 = 24 chunks per row
        const int col = (idx - row * 24) * 8;
        *(bf16x8*)&W1l[row * W1_STRIDE + col] = *(const bf16x8*)&wbf[row * 192 + col];
    }
    #pragma unroll
    for (int it = 0; it < 2; ++it) {
        const int idx = it * 256 + t;           // 0..511
        const int row = idx >> 3;               // 64/8 = 8 chunks per row
        const int col = (idx & 7) * 8;
        *(bf16x8*)&W2l[row * W2_STRIDE + col] = *(const bf16x8*)&wbf[12288 + row * 64 + col];
    }
    __syncthreads();

    const int eA   = e0 + lrow;
    const int eB   = e0 + 16 + lrow;
    const int srcA = gidx(eidx, (size_t)eA, I64);
    const int dstA = gidx(eidx, (size_t)N_EDGES + eA, I64);
    const int srcB = gidx(eidx, (size_t)eB, I64);
    const int dstB = gidx(eidx, (size_t)N_EDGES + eB, I64);

    // GEMM1: K=192, M-blocked x2. A row = [fbuf[src] | efeat[e] | fbuf[dst]].
    f32x4 acc[2][4] = {
        {{0,0,0,0},{0,0,0,0},{0,0,0,0},{0,0,0,0}},
        {{0,0,0,0},{0,0,0,0},{0,0,0,0},{0,0,0,0}}
    };
    #pragma unroll
    for (int k = 0; k < 6; ++k) {
        const int po = (k & 1) * 32 + quad * 8;     // offset within the 64-elem part
        bf16x8 a0, a1;
        if (k < 2) {
            a0 = *(const bf16x8*)&fbuf[(size_t)srcA * D + po];
            a1 = *(const bf16x8*)&fbuf[(size_t)srcB * D + po];
        } else if (k < 4) {
            a0 = ld8(efeat, (size_t)eA * D + po, F32);
            a1 = ld8(efeat, (size_t)eB * D + po, F32);
        } else {
            a0 = *(const bf16x8*)&fbuf[(size_t)dstA * D + po];
            a1 = *(const bf16x8*)&fbuf[(size_t)dstB * D + po];
        }
        #pragma unroll
        for (int n = 0; n < 4; ++n) {
            const bf16x8 b = *(const bf16x8*)&W1l[(n * 16 + lrow) * W1_STRIDE + k * 32 + quad * 8];
            acc[0][n] = MFMA16(a0, b, acc[0][n]);
            acc[1][n] = MFMA16(a1, b, acc[1][n]);
        }
    }

    // ReLU + b1; C-layout -> wave-private LDS (A-layout for GEMM2). No barrier.
    #pragma unroll
    for (int n = 0; n < 4; ++n) {
        const int col  = n * 16 + lrow;
        const float bb = ldf(b1, col, F32);
        #pragma unroll
        for (int m = 0; m < 2; ++m) {
            #pragma unroll
            for (int r = 0; r < 4; ++r) {
                float v = acc[m][n][r] + bb;
                v = v > 0.f ? v : 0.f;
                hs[wave][(m * 16 + quad * 4 + r) * 72 + col] = (bf16)v;
            }
        }
    }

    // GEMM2: K=64, M-blocked x2 (B-fragment reused across M-tiles).
    f32x4 acc2[2][4] = {
        {{0,0,0,0},{0,0,0,0},{0,0,0,0},{0,0,0,0}},
        {{0,0,0,0},{0,0,0,0},{0,0,0,0},{0,0,0,0}}
    };
    #pragma unroll
    for (int k = 0; k < 2; ++k) {
        const bf16x8 a0 = *(const bf16x8*)&hs[wave][lrow * 72 + k * 32 + quad * 8];
        const bf16x8 a1 = *(const bf16x8*)&hs[wave][(16 + lrow) * 72 + k * 32 + quad * 8];
        #pragma unroll
        for (int n = 0; n < 4; ++n) {
            const bf16x8 b = *(const bf16x8*)&W2l[(n * 16 + lrow) * W2_STRIDE + k * 32 + quad * 8];
            acc2[0][n] = MFMA16(a0, b, acc2[0][n]);
            acc2[1][n] = MFMA16(a1, b, acc2[1][n]);
        }
    }

    // h2 + b2 -> hs (reused; all hs reads done), then 32B/lane scattered store.
    #pragma unroll
    for (int n = 0; n < 4; ++n) {
        const int col  = n * 16 + lrow;
        const float bb = ldf(b2, col, F32);
        #pragma unroll
        for (int m = 0; m < 2; ++m) {
            #pragma unroll
            for (int r = 0; r < 4; ++r)
                hs[wave][(m * 16 + quad * 4 + r) * 72 + col] = (bf16)(acc2[m][n][r] + bb);
        }
    }

    const int row = lane >> 2;          // 0..15 (edge row within M-tile)
    const int seg = lane & 3;           // 16-col segment
    #pragma unroll
    for (int m = 0; m < 2; ++m) {
        const int ip  = ipos[e0 + m * 16 + row];
        const bf16x8 v0 = *(const bf16x8*)&hs[wave][(m * 16 + row) * 72 + seg * 16];
        const bf16x8 v1 = *(const bf16x8*)&hs[wave][(m * 16 + row) * 72 + seg * 16 + 8];
        *(bf16x8*)&h2ws[(size_t)ip * D + seg * 16]     = v0;
        *(bf16x8*)&h2ws[(size_t)ip * D + seg * 16 + 8] = v1;
    }
}

// ---------------------------------------------------------------------------
// FAST node kernel (R4): contiguous CSR segment-sum of h2ws, gather unrolled
// 8-deep (16 loads in flight/thread -- was 4-deep; latency-chain limited).
// W3/W4 staged to LDS. 64 nodes/block; gather: 4 lanes per node, 16 cols each.
// ---------------------------------------------------------------------------
__global__ __launch_bounds__(256) void node_fast(
    const bf16* __restrict__ fbuf, const bf16* __restrict__ h2ws,
    const int* __restrict__ rowptr,
    const bf16* __restrict__ wbf, const void* __restrict__ b3, const void* __restrict__ b4,
    void* __restrict__ out, const int* __restrict__ flags)
{
    __shared__ bf16 xs[64 * X2_STRIDE];    // 17408 B
    __shared__ bf16 h3s[64 * HS_STRIDE];   //  9216 B
    __shared__ bf16 W3l[64 * W3_STRIDE];   // 17408 B
    __shared__ bf16 W4l[64 * W4_STRIDE];   //  9216 B

    const int t  = threadIdx.x;
    const int r0 = blockIdx.x * 64;
    const int F32 = flags[0];

    // ---- stage W3 (8192 elems) + W4 (4096 elems) ----
    #pragma unroll
    for (int it = 0; it < 4; ++it) {
        const int idx = it * 256 + t;           // 0..1023
        const int row = idx >> 4;               // 128/8 = 16 chunks per row
        const int col = (idx & 15) * 8;
        *(bf16x8*)&W3l[row * W3_STRIDE + col] = *(const bf16x8*)&wbf[16384 + row * 128 + col];
    }
    #pragma unroll
    for (int it = 0; it < 2; ++it) {
        const int idx = it * 256 + t;           // 0..511
        const int row = idx >> 3;
        const int col = (idx & 7) * 8;
        *(bf16x8*)&W4l[row * W4_STRIDE + col] = *(const bf16x8*)&wbf[24576 + row * 64 + col];
    }

    // segment sum: thread t -> node r0 + (t>>2), col segment (t&3)*16
    {
        const int nloc = t >> 2;
        const int node = r0 + nloc;
        const int seg  = t & 3;
        float accv[16];
        #pragma unroll
        for (int i = 0; i < 16; ++i) accv[i] = 0.f;
        bf16x8 f0 = {0,0,0,0,0,0,0,0}, f1 = {0,0,0,0,0,0,0,0};
        if (node < N_NODES) {
            f0 = *(const bf16x8*)&fbuf[(size_t)node * D + seg * 16];
            f1 = *(const bf16x8*)&fbuf[(size_t)node * D + seg * 16 + 8];
            const int jb = rowptr[node], je = rowptr[node + 1];
            int j = jb;
            for (; j + 8 <= je; j += 8) {
                bf16x8 v[16];
                #pragma unroll
                for (int u = 0; u < 8; ++u) {
                    v[2 * u]     = *(const bf16x8*)&h2ws[(size_t)(j + u) * D + seg * 16];
                    v[2 * u + 1] = *(const bf16x8*)&h2ws[(size_t)(j + u) * D + seg * 16 + 8];
                }
                #pragma unroll
                for (int u = 0; u < 8; ++u) {
                    #pragma unroll
                    for (int i = 0; i < 8; ++i) {
                        accv[i]     += (float)v[2 * u][i];
                        accv[i + 8] += (float)v[2 * u + 1][i];
                    }
                }
            }
            for (; j + 2 <= je; j += 2) {
                const bf16x8 a0 = *(const bf16x8*)&h2ws[(size_t)j * D + seg * 16];
                const bf16x8 a1 = *(const bf16x8*)&h2ws[(size_t)j * D + seg * 16 + 8];
                const bf16x8 c0 = *(const bf16x8*)&h2ws[(size_t)(j + 1) * D + seg * 16];
                const bf16x8 c1 = *(const bf16x8*)&h2ws[(size_t)(j + 1) * D + seg * 16 + 8];
                #pragma unroll
                for (int i = 0; i < 8; ++i) {
                    accv[i]     += (float)a0[i] + (float)c0[i];
                    accv[i + 8] += (float)a1[i] + (float)c1[i];
                }
            }
            if (j < je) {
                const bf16x8 a0 = *(const bf16x8*)&h2ws[(size_t)j * D + seg * 16];
                const bf16x8 a1 = *(const bf16x8*)&h2ws[(size_t)j * D + seg * 16 + 8];
                #pragma unroll
                for (int i = 0; i < 8; ++i) {
                    accv[i]     += (float)a0[i];
                    accv[i + 8] += (float)a1[i];
                }
            }
        }
        bf16x8 s0, s1;
        #pragma unroll
        for (int i = 0; i < 8; ++i) {
            s0[i] = (bf16)((float)f0[i] + accv[i]);
            s1[i] = (bf16)((float)f1[i] + accv[i + 8]);
        }
        *(bf16x8*)&xs[nloc * X2_STRIDE + seg * 16]          = f0;
        *(bf16x8*)&xs[nloc * X2_STRIDE + seg * 16 + 8]      = f1;
        *(bf16x8*)&xs[nloc * X2_STRIDE + 64 + seg * 16]     = s0;
        *(bf16x8*)&xs[nloc * X2_STRIDE + 64 + seg * 16 + 8] = s1;
    }
    __syncthreads();

    const int wave = t >> 6;
    const int lane = t & 63;
    const int m0   = wave * 16;
    const int lrow = lane & 15;
    const int quad = lane >> 4;

    // GEMM3: K=128
    f32x4 acc[4] = {{0,0,0,0},{0,0,0,0},{0,0,0,0},{0,0,0,0}};
    #pragma unroll
    for (int k = 0; k < 4; ++k) {
        const bf16x8 a = *(const bf16x8*)&xs[(m0 + lrow) * X2_STRIDE + k * 32 + quad * 8];
        #pragma unroll
        for (int n = 0; n < 4; ++n) {
            const bf16x8 b = *(const bf16x8*)&W3l[(n * 16 + lrow) * W3_STRIDE + k * 32 + quad * 8];
            acc[n] = MFMA16(a, b, acc[n]);
        }
    }

    #pragma unroll
    for (int n = 0; n < 4; ++n) {
        const int col  = n * 16 + lrow;
        const float bb = ldf(b3, col, F32);
        #pragma unroll
        for (int r = 0; r < 4; ++r) {
            float v = acc[n][r] + bb;
            v = v > 0.f ? v : 0.f;
            h3s[(m0 + quad * 4 + r) * HS_STRIDE + col] = (bf16)v;
        }
    }

    // GEMM4: K=64 (h3s rows are wave-private; no barrier needed)
    f32x4 acc2[4] = {{0,0,0,0},{0,0,0,0},{0,0,0,0},{0,0,0,0}};
    #pragma unroll
    for (int k = 0; k < 2; ++k) {
        const bf16x8 a = *(const bf16x8*)&h3s[(m0 + lrow) * HS_STRIDE + k * 32 + quad * 8];
        #pragma unroll
        for (int n = 0; n < 4; ++n) {
            const bf16x8 b = *(const bf16x8*)&W4l[(n * 16 + lrow) * W4_STRIDE + k * 32 + quad * 8];
            acc2[n] = MFMA16(a, b, acc2[n]);
        }
    }

    #pragma unroll
    for (int n = 0; n < 4; ++n) {
        const int col  = n * 16 + lrow;
        const float bb = ldf(b4, col, F32);
        #pragma unroll
        for (int r = 0; r < 4; ++r) {
            const int node = r0 + m0 + quad * 4 + r;
            if (node < N_NODES) {
                const float v = acc2[n][r] + bb;
                if (F32) ((float*)out)[(size_t)node * D + col] = v;
                else     ((bf16*)out)[(size_t)node * D + col] = (bf16)v;
            }
        }
    }
}

// ---------------------------------------------------------------------------
// SLOW fallback = proven kernels (global f32 atomic scatter), used only
// if ws_size is too small for the fast path.
// ---------------------------------------------------------------------------
__global__ __launch_bounds__(256) void edge_slow(
    const void* __restrict__ feat, const void* __restrict__ eidx,
    const void* __restrict__ efeat,
    const void* __restrict__ W1, const void* __restrict__ b1,
    const void* __restrict__ W2, const void* __restrict__ b2,
    float* __restrict__ sbuf, const int* __restrict__ flags)
{
    __shared__ bf16 xs[64 * XS_STRIDE];
    __shared__ bf16 h1s[64 * HS_STRIDE];
    __shared__ int  srcs[64];
    __shared__ int  fl[2];

    const int t  = threadIdx.x;
    const int e0 = blockIdx.x * 64;

    if (t < 2) fl[t] = flags[t];
    __syncthreads();
    const int F32 = fl[0], I64 = fl[1];

    if (t < 64) srcs[t] = gidx(eidx, e0 + t, I64);

    for (int i = t; i < 64 * 24; i += 256) {
        const int e    = i / 24;
        const int c    = i - e * 24;
        const int part = c >> 3;
        const int cc   = c & 7;
        size_t off;
        const void* base;
        if (part == 0)      { base = feat;  off = (size_t)gidx(eidx, e0 + e, I64) * D + cc * 8; }
        else if (part == 1) { base = efeat; off = (size_t)(e0 + e) * D + cc * 8; }
        else                { base = feat;  off = (size_t)gidx(eidx, (size_t)N_EDGES + e0 + e, I64) * D + cc * 8; }
        *(bf16x8*)&xs[e * XS_STRIDE + part * 64 + cc * 8] = ld8(base, off, F32);
    }
    __syncthreads();

    const int wave = t >> 6;
    const int lane = t & 63;
    const int m0   = wave * 16;
    const int lrow = lane & 15;
    const int quad = lane >> 4;

    f32x4 acc[4] = {{0,0,0,0},{0,0,0,0},{0,0,0,0},{0,0,0,0}};
    #pragma unroll
    for (int k = 0; k < 6; ++k) {
        const bf16x8 a = *(const bf16x8*)&xs[(m0 + lrow) * XS_STRIDE + k * 32 + quad * 8];
        #pragma unroll
        for (int n = 0; n < 4; ++n) {
            const bf16x8 b = ld8(W1, (size_t)(n * 16 + lrow) * 192 + k * 32 + quad * 8, F32);
            acc[n] = MFMA16(a, b, acc[n]);
        }
    }

    #pragma unroll
    for (int n = 0; n < 4; ++n) {
        const int col  = n * 16 + lrow;
        const float bb = ldf(b1, col, F32);
        #pragma unroll
        for (int r = 0; r < 4; ++r) {
            float v = acc[n][r] + bb;
            v = v > 0.f ? v : 0.f;
            h1s[(m0 + quad * 4 + r) * HS_STRIDE + col] = (bf16)v;
        }
    }
    __syncthreads();

    f32x4 acc2[4] = {{0,0,0,0},{0,0,0,0},{0,0,0,0},{0,0,0,0}};
    #pragma unroll
    for (int k = 0; k < 2; ++k) {
        const bf16x8 a = *(const bf16x8*)&h1s[(m0 + lrow) * HS_STRIDE + k * 32 + quad * 8];
        #pragma unroll
        for (int n = 0; n < 4; ++n) {
            const bf16x8 b = ld8(W2, (size_t)(n * 16 + lrow) * D + k * 32 + quad * 8, F32);
            acc2[n] = MFMA16(a, b, acc2[n]);
        }
    }

    #pragma unroll
    for (int n = 0; n < 4; ++n) {
        const int col  = n * 16 + lrow;
        const float bb = ldf(b2, col, F32);
        #pragma unroll
        for (int r = 0; r < 4; ++r) {
            const int e = m0 + quad * 4 + r;
            atomicAdd(&sbuf[(size_t)srcs[e] * D + col], acc2[n][r] + bb);
        }
    }
}

__global__ __launch_bounds__(256) void node_slow(
    const void* __restrict__ feat, const float* __restrict__ sbuf,
    const void* __restrict__ W3, const void* __restrict__ b3,
    const void* __restrict__ W4, const void* __restrict__ b4,
    void* __restrict__ out, const int* __restrict__ flags)
{
    __shared__ bf16 xs[64 * X2_STRIDE];
    __shared__ bf16 h3s[64 * HS_STRIDE];
    __shared__ int fl[1];

    const int t  = threadIdx.x;
    const int r0 = blockIdx.x * 64;

    if (t == 0) fl[0] = flags[0];
    __syncthreads();
    const int F32 = fl[0];

    for (int i = t; i < 64 * 8; i += 256) {
        const int r    = i >> 3;
        const int c    = i & 7;
        const int node = r0 + r;
        bf16x8 fv = {0,0,0,0,0,0,0,0};
        bf16x8 sv = {0,0,0,0,0,0,0,0};
        if (node < N_NODES) {
            fv = ld8(feat, (size_t)node * D + c * 8, F32);
            const float4 sa = *(const float4*)&sbuf[(size_t)node * D + c * 8];
            const float4 sb = *(const float4*)&sbuf[(size_t)node * D + c * 8 + 4];
            sv[0] = (bf16)((float)fv[0] + sa.x);
            sv[1] = (bf16)((float)fv[1] + sa.y);
            sv[2] = (bf16)((float)fv[2] + sa.z);
            sv[3] = (bf16)((float)fv[3] + sa.w);
            sv[4] = (bf16)((float)fv[4] + sb.x);
            sv[5] = (bf16)((float)fv[5] + sb.y);
            sv[6] = (bf16)((float)fv[6] + sb.z);
            sv[7] = (bf16)((float)fv[7] + sb.w);
        }
        *(bf16x8*)&xs[r * X2_STRIDE + c * 8]      = fv;
        *(bf16x8*)&xs[r * X2_STRIDE + 64 + c * 8] = sv;
    }
    __syncthreads();

    const int wave = t >> 6;
    const int lane = t & 63;
    const int m0   = wave * 16;
    const int lrow = lane & 15;
    const int quad = lane >> 4;

    f32x4 acc[4] = {{0,0,0,0},{0,0,0,0},{0,0,0,0},{0,0,0,0}};
    #pragma unroll
    for (int k = 0; k < 4; ++k) {
        const bf16x8 a = *(const bf16x8*)&xs[(m0 + lrow) * X2_STRIDE + k * 32 + quad * 8];
        #pragma unroll
        for (int n = 0; n < 4; ++n) {
            const bf16x8 b = ld8(W3, (size_t)(n * 16 + lrow) * 128 + k * 32 + quad * 8, F32);
            acc[n] = MFMA16(a, b, acc[n]);
        }
    }

    #pragma unroll
    for (int n = 0; n < 4; ++n) {
        const int col  = n * 16 + lrow;
        const float bb = ldf(b3, col, F32);
        #pragma unroll
        for (int r = 0; r < 4; ++r) {
            float v = acc[n][r] + bb;
            v = v > 0.f ? v : 0.f;
            h3s[(m0 + quad * 4 + r) * HS_STRIDE + col] = (bf16)v;
        }
    }
    __syncthreads();

    f32x4 acc2[4] = {{0,0,0,0},{0,0,0,0},{0,0,0,0},{0,0,0,0}};
    #pragma unroll
    for (int k = 0; k < 2; ++k) {
        const bf16x8 a = *(const bf16x8*)&h3s[(m0 + lrow) * HS_STRIDE + k * 32 + quad * 8];
        #pragma unroll
        for (int n = 0; n < 4; ++n) {
            const bf16x8 b = ld8(W4, (size_t)(n * 16 + lrow) * D + k * 32 + quad * 8, F32);
            acc2[n] = MFMA16(a, b, acc2[n]);
        }
    }

    #pragma unroll
    for (int n = 0; n < 4; ++n) {
        const int col  = n * 16 + lrow;
        const float bb = ldf(b4, col, F32);
        #pragma unroll
        for (int r = 0; r < 4; ++r) {
            const int node = r0 + m0 + quad * 4 + r;
            if (node < N_NODES) {
                const float v = acc2[n][r] + bb;
                if (F32) ((float*)out)[(size_t)node * D + col] = v;
                else     ((bf16*)out)[(size_t)node * D + col] = (bf16)v;
            }
        }
    }
}

extern "C" void kernel_launch(void* const* d_in, const int* in_sizes, int n_in,
                              void* d_out, int out_size, void* d_ws, size_t ws_size,
                              hipStream_t stream) {
    const void* feat  = d_in[0];
    const void* eidx  = d_in[1];
    const void* efeat = d_in[2];
    const void* W1    = d_in[3];
    const void* b1    = d_in[4];
    const void* W2    = d_in[5];
    const void* b2    = d_in[6];
    const void* W3    = d_in[7];
    const void* b3    = d_in[8];
    const void* W4    = d_in[9];
    const void* b4    = d_in[10];

    char* ws = (char*)d_ws;

    if (ws_size >= WS_FAST_NEED) {
        bf16* fbuf   = (bf16*)(ws + OFF_FBUF);
        bf16* h2ws   = (bf16*)(ws + OFF_H2);
        int*  ipos   = (int*)(ws + OFF_IPOS);
        int*  rowptr = (int*)(ws + OFF_ROWPTR);
        int*  cursor = (int*)(ws + OFF_CURSOR);
        int*  counts = (int*)(ws + OFF_COUNTS);
        bf16* wbf    = (bf16*)(ws + OFF_WBF);
        int*  flags  = (int*)(ws + OFF_FLAGS);

        detect_kernel<<<1, 64, 0, stream>>>(feat, eidx, flags);
        hipMemsetAsync(counts, 0, (size_t)N_NODES * sizeof(int), stream);
        prep_kernel<<<1, 256, 0, stream>>>(W1, W2, W3, W4, wbf, flags);
        conv_feat_kernel<<<3125, 256, 0, stream>>>(feat, fbuf, flags);
        hist_kernel<<<N_EDGES / 256, 256, 0, stream>>>(eidx, counts, flags);
        scan_kernel<<<1, 256, 0, stream>>>(counts, rowptr, cursor);
        fill_kernel<<<N_EDGES / 256, 256, 0, stream>>>(eidx, cursor, ipos, flags);
        edge_fast<<<N_EDGES / 128, 256, 0, stream>>>(fbuf, eidx, efeat, wbf, b1, b2,
                                                     ipos, h2ws, flags);
        node_fast<<<(N_NODES + 63) / 64, 256, 0, stream>>>(fbuf, h2ws, rowptr,
                                                           wbf, b3, b4, d_out, flags);
    } else {
        float* sbuf  = (float*)(ws + S_SBUF);
        int*   flags = (int*)(ws + S_FLAGS);

        detect_kernel<<<1, 64, 0, stream>>>(feat, eidx, flags);
        hipMemsetAsync(sbuf, 0, (size_t)N_NODES * D * sizeof(float), stream);
        edge_slow<<<N_EDGES / 64, 256, 0, stream>>>(feat, eidx, efeat, W1, b1, W2, b2,
                                                    sbuf, flags);
        node_slow<<<(N_NODES + 63) / 64, 256, 0, stream>>>(feat, sbuf, W3, b3, W4, b4,
                                                           d_out, flags);
    }
}